// Round 1
// baseline (355.803 us; speedup 1.0000x reference)
//
#include <hip/hip_runtime.h>

// sigma = 1e-4  ->  1/sigma = 1e4
#define INV_SIGMA 1.0e4f

__device__ __forceinline__ float one_minus_prob(float d, int f) {
    // factor = (f >= 0) ? (1 - sigmoid(-d/sigma)) : 1
    //        = (f >= 0) ? sigmoid(d/sigma)        : 1
    float s = 1.0f / (1.0f + __expf(-d * INV_SIGMA));
    return (f >= 0) ? s : 1.0f;
}

__global__ __launch_bounds__(256) void SelfShader_9921374454199_kernel(
    const float* __restrict__ zbuf,
    const float* __restrict__ dists,
    const int*   __restrict__ p2f,
    float*       __restrict__ out,
    int P)  // P = N*H*W pixels, K = 16
{
    int i = blockIdx.x * blockDim.x + threadIdx.x;
    if (i >= P) return;

    size_t base = (size_t)i * 16;

    const float4* d4 = reinterpret_cast<const float4*>(dists + base);
    const int4*   f4 = reinterpret_cast<const int4*>(p2f + base);

    float prod = 1.0f;
#pragma unroll
    for (int j = 0; j < 4; ++j) {
        float4 d = d4[j];
        int4   f = f4[j];
        prod *= one_minus_prob(d.x, f.x);
        prod *= one_minus_prob(d.y, f.y);
        prod *= one_minus_prob(d.z, f.z);
        prod *= one_minus_prob(d.w, f.w);
    }

    float alpha = 1.0f - prod;
    float z = zbuf[base];  // zbuf[..., 0]

    float4 o = make_float4(z, z, z, alpha);
    reinterpret_cast<float4*>(out)[i] = o;
}

extern "C" void kernel_launch(void* const* d_in, const int* in_sizes, int n_in,
                              void* d_out, int out_size, void* d_ws, size_t ws_size,
                              hipStream_t stream) {
    const float* zbuf  = (const float*)d_in[0];
    const float* dists = (const float*)d_in[1];
    const int*   p2f   = (const int*)d_in[2];
    float*       out   = (float*)d_out;

    int P = in_sizes[0] / 16;  // N*H*W
    int block = 256;
    int grid  = (P + block - 1) / block;
    SelfShader_9921374454199_kernel<<<grid, block, 0, stream>>>(zbuf, dists, p2f, out, P);
}